// Round 10
// baseline (225.767 us; speedup 1.0000x reference)
//
#include <hip/hip_runtime.h>
#include <hip/hip_bf16.h>
#include <stdint.h>

// ---- problem dims (fixed) ----
#define B_   8
#define S_   2048
#define D_   768
#define BS_  16384   // B_*S_
#define F_   1536    // 2*D_

typedef __attribute__((ext_vector_type(8))) short short8;    // 8 bf16 MFMA frag
typedef __attribute__((ext_vector_type(4))) float f32x4;     // 16x16 acc frag
typedef __attribute__((ext_vector_type(4))) float float4v;
typedef __attribute__((ext_vector_type(4))) unsigned short ushort4v;

__device__ __forceinline__ unsigned short f2bf(float f) {
  union { float f; unsigned u; } v; v.f = f;
  unsigned r = v.u + 0x7FFFu + ((v.u >> 16) & 1u);   // RNE
  return (unsigned short)(r >> 16);
}
__device__ __forceinline__ float bf2f(unsigned short h) {
  union { unsigned u; float f; } v; v.u = ((unsigned)h) << 16;
  return v.f;
}
__device__ __forceinline__ unsigned cvtpk_bf16(float lo, float hi) {
  unsigned r; asm("v_cvt_pk_bf16_f32 %0, %1, %2" : "=v"(r) : "v"(lo), "v"(hi)); return r;
}

#define GLOAD16(gp, lp) \
  __builtin_amdgcn_global_load_lds((const __attribute__((address_space(1))) void*)(gp), \
                                   (__attribute__((address_space(3))) void*)(lp), 16, 0, 0)
#define VMC(n) asm volatile("s_waitcnt vmcnt(" #n ")" ::: "memory")

// ---------------- fused cast kernel: two f32->bf16 streams, 8 elem/thread each --------
__global__ __launch_bounds__(256) void k_cast8x2(const float* __restrict__ s1,
                                                 const float* __restrict__ s2,
                                                 unsigned short* __restrict__ d1,
                                                 unsigned short* __restrict__ d2, int n) {
  int i = (blockIdx.x * 256 + threadIdx.x) * 8;
  if (i >= n) return;
  {
    float4v a = *(const float4v*)(s1 + i);
    float4v b2 = *(const float4v*)(s1 + i + 4);
    union { short8 s; unsigned u[4]; } o;
    o.u[0] = cvtpk_bf16(a[0], a[1]); o.u[1] = cvtpk_bf16(a[2], a[3]);
    o.u[2] = cvtpk_bf16(b2[0], b2[1]); o.u[3] = cvtpk_bf16(b2[2], b2[3]);
    *(short8*)(d1 + i) = o.s;
  }
  {
    float4v a = *(const float4v*)(s2 + i);
    float4v b2 = *(const float4v*)(s2 + i + 4);
    union { short8 s; unsigned u[4]; } o;
    o.u[0] = cvtpk_bf16(a[0], a[1]); o.u[1] = cvtpk_bf16(a[2], a[3]);
    o.u[2] = cvtpk_bf16(b2[0], b2[1]); o.u[3] = cvtpk_bf16(b2[2], b2[3]);
    *(short8*)(d2 + i) = o.s;
  }
}

// src[R][C] f32 -> dst[C][R] bf16   (R,C multiples of 32)
__global__ __launch_bounds__(256) void k_transpose_cast(const float* __restrict__ src,
                                                        unsigned short* __restrict__ dst,
                                                        int R, int C) {
  __shared__ float tile[32][33];
  int bx = blockIdx.x * 32;   // C index
  int by = blockIdx.y * 32;   // R index
  int tx = threadIdx.x, ty = threadIdx.y;   // block (32,8)
#pragma unroll
  for (int k = 0; k < 32; k += 8)
    tile[ty + k][tx] = src[(size_t)(by + ty + k) * C + bx + tx];
  __syncthreads();
#pragma unroll
  for (int k = 0; k < 32; k += 8)
    dst[(size_t)(bx + ty + k) * R + by + tx] = f2bf(tile[tx][ty + k]);
}

// ---------------- GEMM v3: 4-slab k32 rotation pipeline ----------------
// C[M][768or..] = [A|A2][M][K] * BT[N][K]^T.  Tile 128m x 192n, 4 waves (2m x 2n),
// wave 64x96 (4x6 frags of 16x16x32). LDS: 4 rotating slabs of (128A+192B)x32 bf16
// = 20KB each (80KB dynamic, 2 blocks/CU). Per step: vmcnt(10) [drain own stage-j,
// keep j+1,j+2 in flight] -> barrier -> stage(j+3) -> 10 ds_read -> 24 MFMA.
// Race-free: all waves drain their stage-j loads BEFORE the barrier; stage(j+3)
// overwrites the slab whose reads all waves completed before this barrier.
// EPI=0: f32 out + bias.  EPI=1: bf16 out [M][768] via 48KB LDS restage.
template <int EPI>
__global__ __launch_bounds__(256, 2) void k_gemm(const unsigned short* __restrict__ A,
                                                 const unsigned short* __restrict__ A2,
                                                 const unsigned short* __restrict__ BT,
                                                 int K, int Ksplit,
                                                 float* __restrict__ outF,
                                                 const float* __restrict__ bias,
                                                 unsigned short* __restrict__ outT) {
  extern __shared__ unsigned short lds[];   // 4 * 10240 ushort = 80KB
  int lin = blockIdx.x;                     // 512 blocks, bijective XCD chunk
  int nl  = (lin & 7) * 64 + (lin >> 3);
  int mBase = (nl >> 2) * 128;
  int nBase = (nl & 3) * 192;
  int t = threadIdx.x;
  int w = t >> 6, l = t & 63;
  int lm = l & 15, lg = l >> 4;
  int wm = w >> 1, wn = w & 1;   // wave: rows [wm*64,+64), cols [wn*96,+96)
  f32x4 acc[4][6] = {};
  const int NS = K >> 5;         // k32 steps (24 or 48)

  auto stage = [&](int j) {
    unsigned short* sl = lds + (j & 3) * 10240;
    int kk = j * 32;
    const unsigned short* As = (kk < Ksplit) ? A : A2;
    int ka = (kk < Ksplit) ? kk : kk - Ksplit;
#pragma unroll
    for (int i = 0; i < 2; ++i) {          // A: 128 rows x 4 slots = 512 slots
      int g = i * 256 + t;
      int r = g >> 2, p = g & 3;
      GLOAD16(As + (size_t)(mBase + r) * 768 + ka + ((p ^ (r & 3)) * 8),
              (char*)sl + i * 4096 + w * 1024);
    }
#pragma unroll
    for (int i = 0; i < 3; ++i) {          // B: 192 rows x 4 slots = 768 slots
      int g = i * 256 + t;
      int r = g >> 2, p = g & 3;
      GLOAD16(BT + (size_t)(nBase + r) * K + kk + ((p ^ (r & 3)) * 8),
              (char*)sl + 8192 + i * 4096 + w * 1024);
    }
  };

  stage(0); stage(1); stage(2);
  for (int j = 0; j < NS; ++j) {
    if (j + 2 < NS)      { VMC(10); }      // drain own stage-j; j+1,j+2 stay in flight
    else if (j + 1 < NS) { VMC(5); }
    else                 { VMC(0); }
    __builtin_amdgcn_s_barrier();          // slab j complete (all waves drained)
    __builtin_amdgcn_sched_barrier(0);
    if (j + 3 < NS) stage(j + 3);          // into slab read at step j-1 (safe)
    const unsigned short* sl = lds + (j & 3) * 10240;
    short8 af[4], bfv[6];
#pragma unroll
    for (int mf = 0; mf < 4; ++mf) {
      int r = wm * 64 + mf * 16 + lm;
      af[mf] = *(const short8*)(sl + (r * 4 + (lg ^ (r & 3))) * 8);
    }
#pragma unroll
    for (int nf = 0; nf < 6; ++nf) {
      int r = wn * 96 + nf * 16 + lm;
      bfv[nf] = *(const short8*)(sl + 4096 + (r * 4 + (lg ^ (r & 3))) * 8);
    }
    __builtin_amdgcn_s_setprio(1);
#pragma unroll
    for (int mf = 0; mf < 4; ++mf)
#pragma unroll
      for (int nf = 0; nf < 6; ++nf)
        acc[mf][nf] = __builtin_amdgcn_mfma_f32_16x16x32_bf16(af[mf], bfv[nf], acc[mf][nf], 0, 0, 0);
    __builtin_amdgcn_s_setprio(0);
  }

  if (EPI == 0) {
#pragma unroll
    for (int mf = 0; mf < 4; ++mf) {
      int m = mBase + wm * 64 + mf * 16 + lg * 4;
#pragma unroll
      for (int nf = 0; nf < 6; ++nf) {
        int n = nBase + wn * 96 + nf * 16 + lm;
        float bv = bias[n];
#pragma unroll
        for (int r = 0; r < 4; ++r)
          outF[(size_t)(m + r) * 768 + n] = acc[mf][nf][r] + bv;
      }
    }
  } else {
    // restage [128][192] bf16 into LDS (bijective XOR within 8-chunk groups), then
    // coalesced row stores.
    __syncthreads();                       // all waves done with slabs
#pragma unroll
    for (int mf = 0; mf < 4; ++mf)
#pragma unroll
      for (int nf = 0; nf < 6; ++nf) {
        int col = wn * 96 + nf * 16 + lm;
        int cq = col >> 3;
#pragma unroll
        for (int r = 0; r < 4; ++r) {
          int row = wm * 64 + mf * 16 + lg * 4 + r;
          int phys = (cq & 24) | ((cq & 7) ^ (row & 7));
          lds[row * 192 + phys * 8 + (col & 7)] = f2bf(acc[mf][nf][r]);
        }
      }
    __syncthreads();
    int row = t >> 1;
    int qb = (t & 1) * 12;
#pragma unroll
    for (int s = 0; s < 12; ++s) {
      int cq = qb + s;
      int phys = (cq & 24) | ((cq & 7) ^ (row & 7));
      short8 v = *(const short8*)(lds + row * 192 + phys * 8);
      *(short8*)(outT + (size_t)(mBase + row) * 768 + nBase + cq * 8) = v;
    }
  }
}

// ---------------- alphas: as/ad[b][s] = xp[b][s][:] . a_{src,dst} ----------------
__global__ __launch_bounds__(256) void k_alphas(const unsigned short* __restrict__ xp,
                                                const float* __restrict__ a_src,
                                                const float* __restrict__ a_dst,
                                                float* __restrict__ as, float* __restrict__ ad) {
  int b = blockIdx.y;
  int w = threadIdx.x >> 6, lane = threadIdx.x & 63;
  float sv[12], dv[12];
#pragma unroll
  for (int q = 0; q < 3; ++q) {
    *(float4v*)(sv + q * 4) = *(const float4v*)(a_src + lane * 12 + q * 4);
    *(float4v*)(dv + q * 4) = *(const float4v*)(a_dst + lane * 12 + q * 4);
  }
  int r0 = blockIdx.x * 64 + w * 16;
  for (int rr = 0; rr < 16; ++rr) {
    int row = r0 + rr;
    const unsigned short* px = xp + ((size_t)b * S_ + row) * D_ + lane * 12;
    float accs = 0.f, accd = 0.f;
#pragma unroll
    for (int q = 0; q < 3; ++q) {
      ushort4v xv = *(const ushort4v*)(px + q * 4);
#pragma unroll
      for (int e = 0; e < 4; ++e) {
        float x = bf2f(xv[e]);
        accs = fmaf(sv[q * 4 + e], x, accs);
        accd = fmaf(dv[q * 4 + e], x, accd);
      }
    }
#pragma unroll
    for (int m = 32; m; m >>= 1) {
      accs += __shfl_xor(accs, m);
      accd += __shfl_xor(accd, m);
    }
    if (lane == 0) { as[b * S_ + row] = accs; ad[b * S_ + row] = accd; }
  }
}

// ---------------- rank-by-count v2: grid (64, 8), 32 j x 8 k-parts per block ----------
__global__ __launch_bounds__(256) void k_rank(const float* __restrict__ as,
                                              float* __restrict__ ssorted, int* __restrict__ sidx,
                                              float* __restrict__ es1g, float* __restrict__ es2g,
                                              float* __restrict__ msg) {
  __shared__ float sjl[S_];
  __shared__ float red[256];
  __shared__ int rk[32][9];          // 9-pad: bank-conflict-free column reads
  int b = blockIdx.y, t = threadIdx.x;
  float lmx = -1e30f;
#pragma unroll
  for (int q = 0; q < 2; ++q) {
    int p = (t + q * 256) * 4;
    float4v v = *(const float4v*)(as + b * S_ + p);
    *(float4v*)(sjl + p) = v;
    lmx = fmaxf(lmx, fmaxf(fmaxf(v[0], v[1]), fmaxf(v[2], v[3])));
  }
  red[t] = lmx;
  __syncthreads();
  for (int st = 128; st > 0; st >>= 1) {
    if (t < st) red[t] = fmaxf(red[t], red[t + st]);
    __syncthreads();
  }
  float Ms = red[0];
  int jl = t & 31, part = t >> 5;
  int j = blockIdx.x * 32 + jl;
  float sj = sjl[j];
  int r0 = 0, r1 = 0, r2 = 0, r3 = 0;
  int kbase = part * 256;
#pragma unroll 8
  for (int kq = 0; kq < 64; ++kq) {
    int k = kbase + kq * 4;
    float4v sk = *(const float4v*)(sjl + k);       // wave-broadcast per 32 lanes
    r0 += (sk[0] < sj) | ((sk[0] == sj) & (k < j));
    r1 += (sk[1] < sj) | ((sk[1] == sj) & (k + 1 < j));
    r2 += (sk[2] < sj) | ((sk[2] == sj) & (k + 2 < j));
    r3 += (sk[3] < sj) | ((sk[3] == sj) & (k + 3 < j));
  }
  rk[jl][part] = r0 + r1 + r2 + r3;
  __syncthreads();
  if (t < 32) {
    int rank = rk[t][0] + rk[t][1] + rk[t][2] + rk[t][3]
             + rk[t][4] + rk[t][5] + rk[t][6] + rk[t][7];
    int jj = blockIdx.x * 32 + t;
    float sv = sjl[jj];
    ssorted[b * S_ + rank] = sv;
    sidx[b * S_ + rank] = jj;
    es1g[b * S_ + rank] = __expf(sv - Ms);
    es2g[b * S_ + rank] = __expf(0.2f * (sv - Ms));
    if (blockIdx.x == 0 && t == 0) msg[b] = Ms;
  }
}

// ---------------- chunk scalar scans: sufug (suffix) / prevg (exclusive prefix) -------
__global__ __launch_bounds__(256) void k_pscan(const float* __restrict__ es1g,
                                               const float* __restrict__ es2g,
                                               float* __restrict__ sufug,
                                               float* __restrict__ prevg) {
  __shared__ float su[256], pv[256];
  int b = blockIdx.x, t = threadIdx.x;
  float a1 = 0.f, a2 = 0.f;
#pragma unroll
  for (int r = 0; r < 8; ++r) {
    a1 += es1g[b * S_ + t * 8 + r];
    a2 += es2g[b * S_ + t * 8 + r];
  }
  su[t] = a1; pv[t] = a2;
  __syncthreads();
  for (int off = 1; off < 256; off <<= 1) {
    float vs = (t + off < 256) ? su[t + off] : 0.f;   // suffix-inclusive
    float vp = (t >= off) ? pv[t - off] : 0.f;        // prefix-inclusive
    __syncthreads();
    su[t] += vs; pv[t] += vp;
    __syncthreads();
  }
  sufug[b * 260 + t] = su[t];
  prevg[b * 260 + t] = (t > 0) ? pv[t - 1] : 0.f;
  if (t == 0) sufug[b * 260 + 256] = 0.f;
}

// ---------------- chunk sums: SU/SV[b][c][768] over 8 sorted rows each ----------------
__global__ __launch_bounds__(192) void k_chunks(const unsigned short* __restrict__ xp,
                                                const int* __restrict__ sidx,
                                                const float* __restrict__ es1g,
                                                const float* __restrict__ es2g,
                                                float* __restrict__ SU, float* __restrict__ SV) {
  __shared__ int ridx[64];
  __shared__ float w1l[64], w2l[64];
  int b = blockIdx.y, cblk = blockIdx.x;   // 32 cblks x 8 chunks
  int t = threadIdx.x;
  if (t < 64) {
    int r = cblk * 64 + t;
    ridx[t] = sidx[b * S_ + r];
    w1l[t] = es1g[b * S_ + r];
    w2l[t] = es2g[b * S_ + r];
  }
  __syncthreads();
  int d0 = t * 4;
  const unsigned short* xb = xp + (size_t)b * S_ * D_;
  for (int q = 0; q < 8; ++q) {
    float a1[4] = {0.f, 0.f, 0.f, 0.f}, a2[4] = {0.f, 0.f, 0.f, 0.f};
#pragma unroll
    for (int r = 0; r < 8; ++r) {
      int j = q * 8 + r;
      ushort4v xv = *(const ushort4v*)(xb + (size_t)ridx[j] * D_ + d0);
      float w1 = w1l[j], w2 = w2l[j];
#pragma unroll
      for (int e = 0; e < 4; ++e) {
        float x = bf2f(xv[e]);
        a1[e] = fmaf(w1, x, a1[e]);
        a2[e] = fmaf(w2, x, a2[e]);
      }
    }
    int c = cblk * 8 + q;
    float4v o1, o2;
    o1[0] = a1[0]; o1[1] = a1[1]; o1[2] = a1[2]; o1[3] = a1[3];
    o2[0] = a2[0]; o2[1] = a2[1]; o2[2] = a2[2]; o2[3] = a2[3];
    *(float4v*)(SU + ((size_t)b * 257 + c) * D_ + d0) = o1;
    *(float4v*)(SV + ((size_t)b * 256 + c) * D_ + d0) = o2;
  }
}

// ---------------- in-place scans over chunks: SU -> suffix, SV -> exclusive prefix ----
__global__ __launch_bounds__(256) void k_scan(float* __restrict__ SU, float* __restrict__ SV) {
  int b = blockIdx.y;
  int d = blockIdx.x * 256 + threadIdx.x;   // grid (3, 8)
  float* u = SU + (size_t)b * 257 * D_ + d;
  float* v = SV + (size_t)b * 256 * D_ + d;
  u[(size_t)256 * D_] = 0.f;
  float s = 0.f;
#pragma unroll 4
  for (int c = 255; c >= 0; --c) { s += u[(size_t)c * D_]; u[(size_t)c * D_] = s; }
  float p = 0.f;
#pragma unroll 4
  for (int c = 0; c < 256; ++c) { float tv = v[(size_t)c * D_]; v[(size_t)c * D_] = p; p += tv; }
}

// ---------------- output v3: 16-i tiles, 1024 blocks (4/CU) ----------------
__global__ __launch_bounds__(256) void k_out(const unsigned short* __restrict__ xp,
                                             const float* __restrict__ ad,
                                             const float* __restrict__ ssorted,
                                             const int* __restrict__ sidx,
                                             const float* __restrict__ es1g,
                                             const float* __restrict__ es2g,
                                             const float* __restrict__ sufug,
                                             const float* __restrict__ prevg,
                                             const float* __restrict__ msg,
                                             const float* __restrict__ SU,
                                             const float* __restrict__ SV,
                                             const float* __restrict__ b_gat,
                                             unsigned short* __restrict__ gout) {
  __shared__ float skeys[2048];
  __shared__ float G1[16], G2[16], WL[16][8];
  __shared__ int CI[16], RI[16][8];
  int bid = blockIdx.x;                 // 1024 blocks; bid&7 = batch (XCD affinity)
  int b = bid & 7, itile = bid >> 3;    // itile 0..127
  int i0 = itile * 16;
  int t = threadIdx.x;
#pragma unroll
  for (int k2 = 0; k2 < 2; ++k2) {
    int p = (t + k2 * 256) * 4;
    *(float4v*)(skeys + p) = *(const float4v*)(ssorted + b * S_ + p);
  }
  __syncthreads();
  if (t < 16) {
    int i = i0 + t;
    float di = ad[b * S_ + i];
    float thr = -di;
    int lo = 0, hi = 2048;
#pragma unroll
    for (int st = 0; st < 11; ++st) {
      int mid = (lo + hi) >> 1;
      if (skeys[mid] <= thr) lo = mid + 1; else hi = mid;
    }
    int c = lo >> 3; if (c > 255) c = 255;
    float t1 = di + msg[b];
    float mst = fmaxf(t1, 0.2f * t1);
    float g1 = __expf(t1 - mst), g2 = __expf(0.2f * t1 - mst);
    float den = g1 * sufug[b * 260 + c + 1] + g2 * prevg[b * 260 + c];
    float wr[8]; int rid[8];
#pragma unroll
    for (int r = 0; r < 8; ++r) {
      int row = c * 8 + r;
      bool neg = (skeys[row] <= thr);
      float wv = neg ? g2 * es2g[b * S_ + row] : g1 * es1g[b * S_ + row];
      den += wv;
      wr[r] = wv;
      rid[r] = sidx[b * S_ + row];
    }
    float inv = 1.f / den;
    G1[t] = g1 * inv; G2[t] = g2 * inv; CI[t] = c;
#pragma unroll
    for (int r = 0; r < 8; ++r) { WL[t][r] = wr[r] * inv; RI[t][r] = rid[r]; }
  }
  __syncthreads();
  int d0 = t * 3;
  float bg0 = b_gat[d0], bg1 = b_gat[d0 + 1], bg2 = b_gat[d0 + 2];
  const unsigned short* xb = xp + (size_t)b * S_ * D_;
  const float* SUb = SU + (size_t)b * 257 * D_;
  const float* SVb = SV + (size_t)b * 256 * D_;
  for (int ii = 0; ii < 16; ++ii) {
    int c = CI[ii];
    float g1 = G1[ii], g2 = G2[ii];
    const float* urow = SUb + (size_t)(c + 1) * D_ + d0;
    const float* vrow = SVb + (size_t)c * D_ + d0;
    float o0 = fmaf(g1, urow[0], g2 * vrow[0]);
    float o1 = fmaf(g1, urow[1], g2 * vrow[1]);
    float o2 = fmaf(g1, urow[2], g2 * vrow[2]);
#pragma unroll
    for (int r = 0; r < 8; ++r) {
      float wv = WL[ii][r];
      const unsigned short* xr = xb + (size_t)RI[ii][r] * D_ + d0;
      o0 = fmaf(wv, bf2f(xr[0]), o0);
      o1 = fmaf(wv, bf2f(xr[1]), o1);
      o2 = fmaf(wv, bf2f(xr[2]), o2);
    }
    unsigned short* go = gout + ((size_t)b * S_ + i0 + ii) * D_ + d0;
    go[0] = f2bf(o0 + bg0); go[1] = f2bf(o1 + bg1); go[2] = f2bf(o2 + bg2);
  }
}

// ---------------- launch ----------------
extern "C" void kernel_launch(void* const* d_in, const int* in_sizes, int n_in,
                              void* d_out, int out_size, void* d_ws, size_t ws_size,
                              hipStream_t stream) {
  const float* hs   = (const float*)d_in[0];
  const float* to   = (const float*)d_in[1];
  const float* Wg   = (const float*)d_in[2];
  const float* asrc = (const float*)d_in[3];
  const float* adst = (const float*)d_in[4];
  const float* bg   = (const float*)d_in[5];
  const float* Wf   = (const float*)d_in[6];
  const float* bfu  = (const float*)d_in[7];
  float* out = (float*)d_out;

  char* ws = (char*)d_ws;
  size_t off = 0;
  auto alloc = [&](size_t bytes) {
    char* p = ws + off;
    off += (bytes + 255) & ~(size_t)255;
    return p;
  };
  unsigned short* hs_bf = (unsigned short*)alloc((size_t)BS_ * D_ * 2);  // reused as gout
  unsigned short* to_bf = (unsigned short*)alloc((size_t)BS_ * D_ * 2);
  unsigned short* xp    = (unsigned short*)alloc((size_t)BS_ * D_ * 2);
  unsigned short* WgT   = (unsigned short*)alloc((size_t)D_ * D_ * 2);
  unsigned short* WfT   = (unsigned short*)alloc((size_t)D_ * F_ * 2);
  float* as   = (float*)alloc((size_t)BS_ * 4);
  float* ad   = (float*)alloc((size_t)BS_ * 4);
  float* ssorted = (float*)alloc((size_t)BS_ * 4);
  int*   sidx    = (int*)alloc((size_t)BS_ * 4);
  float* es1g = (float*)alloc((size_t)BS_ * 4);
  float* es2g = (float*)alloc((size_t)BS_ * 4);
  float* sufug = (float*)alloc((size_t)B_ * 260 * 4);
  float* prevg = (float*)alloc((size_t)B_ * 260 * 4);
  float* msg   = (float*)alloc(256);
  float* SU = (float*)alloc((size_t)B_ * 257 * D_ * 4);   // suffix sums
  float* SV = (float*)alloc((size_t)B_ * 256 * D_ * 4);   // exclusive prefix
  unsigned short* gout = hs_bf;   // hs_bf dead after gemm<1>

  (void)hipFuncSetAttribute((const void*)k_gemm<1>,
                            hipFuncAttributeMaxDynamicSharedMemorySize, 81920);
  (void)hipFuncSetAttribute((const void*)k_gemm<0>,
                            hipFuncAttributeMaxDynamicSharedMemorySize, 81920);

  int n = BS_ * D_;
  k_cast8x2<<<n / 2048, 256, 0, stream>>>(hs, to, hs_bf, to_bf, n);
  k_transpose_cast<<<dim3(D_ / 32, D_ / 32), dim3(32, 8), 0, stream>>>(Wg, WgT, D_, D_);
  k_transpose_cast<<<dim3(D_ / 32, F_ / 32), dim3(32, 8), 0, stream>>>(Wf, WfT, F_, D_);
  k_gemm<1><<<512, 256, 81920, stream>>>(hs_bf, hs_bf, WgT, D_, D_, nullptr, nullptr, xp);
  k_alphas<<<dim3(32, B_), 256, 0, stream>>>(xp, asrc, adst, as, ad);
  k_rank<<<dim3(64, B_), 256, 0, stream>>>(as, ssorted, sidx, es1g, es2g, msg);
  k_pscan<<<B_, 256, 0, stream>>>(es1g, es2g, sufug, prevg);
  k_chunks<<<dim3(32, B_), 192, 0, stream>>>(xp, sidx, es1g, es2g, SU, SV);
  k_scan<<<dim3(3, B_), 256, 0, stream>>>(SU, SV);
  k_out<<<1024, 256, 0, stream>>>(xp, ad, ssorted, sidx, es1g, es2g, sufug, prevg, msg,
                                  SU, SV, bg, gout);
  k_gemm<0><<<512, 256, 81920, stream>>>(to_bf, gout, WfT, F_, D_, out, bfu, nullptr);
}